// Round 3
// baseline (573.622 us; speedup 1.0000x reference)
//
#include <hip/hip_runtime.h>
#include <hip/hip_bf16.h>

static constexpr int F = 64;       // IN_FT == OUT_FT == 64
static constexpr int TOT = 384;    // 6*F columns in fc_w
static constexpr int KEFF = 320;   // effective K after merging duplicate |y1-y2| block

// ---------------- CSR build (counting sort by dst) ----------------

__global__ __launch_bounds__(256) void hist_kernel(
    const int* __restrict__ dst, int* __restrict__ deg, int ne)
{
    int e = blockIdx.x * 256 + threadIdx.x;
    if (e < ne) atomicAdd(&deg[dst[e]], 1);
}

// single-block exclusive scan over n entries (n ~ 50k)
__global__ __launch_bounds__(1024) void scan_kernel(
    const int* __restrict__ deg, int* __restrict__ rowptr,
    int* __restrict__ cursor, int n)
{
    __shared__ int part[1024];
    int tid = threadIdx.x;
    int chunk = (n + 1023) / 1024;
    int lo = tid * chunk;
    int hi = min(lo + chunk, n);
    int s = 0;
    for (int i = lo; i < hi; ++i) s += deg[i];
    part[tid] = s;
    __syncthreads();
    for (int off = 1; off < 1024; off <<= 1) {
        int v = (tid >= off) ? part[tid - off] : 0;
        __syncthreads();
        part[tid] += v;
        __syncthreads();
    }
    int prefix = (tid == 0) ? 0 : part[tid - 1];
    for (int i = lo; i < hi; ++i) {
        rowptr[i] = prefix;
        cursor[i] = prefix;
        prefix += deg[i];
    }
    if (tid == 1023) rowptr[n] = part[1023];
}

__global__ __launch_bounds__(256) void scatter_kernel(
    const int* __restrict__ src, const int* __restrict__ dst,
    const float* __restrict__ ew, int* __restrict__ cursor,
    int* __restrict__ csr_src, float* __restrict__ csr_w, int ne)
{
    int e = blockIdx.x * 256 + threadIdx.x;
    if (e >= ne) return;
    int d = dst[e];
    int pos = atomicAdd(&cursor[d], 1);
    csr_src[pos] = src[e];
    csr_w[pos]   = ew[e];
}

// ---------------- pull spmm: wave = node, 4 x 16-lane gather groups ----------------
// Group g (lanes 16g..16g+15) gathers edge k+g's source row as 16 x float4
// (256 B coalesced). 4 edges in flight per iteration; cross-group reduction
// via 2 rounds of shfl_xor; lanes 0-15 store the 256 B result row.

__global__ __launch_bounds__(256) void spmm_pull4(
    const float* __restrict__ x, float* __restrict__ y,
    const int* __restrict__ rowptr, const int* __restrict__ csr_src,
    const float* __restrict__ csr_w, int n)
{
    int wid  = (blockIdx.x * 256 + threadIdx.x) >> 6;  // node
    int lane = threadIdx.x & 63;
    if (wid >= n) return;
    int beg = rowptr[wid], end = rowptr[wid + 1];
    int g  = lane >> 4;    // edge slot within iteration
    int fi = lane & 15;    // float4 slot within feature row

    float ax = 0.0f, ay = 0.0f, az = 0.0f, aw = 0.0f;
    for (int k = beg; k < end; k += 4) {
        int e = k + g;
        float w = 0.0f;
        int   s = 0;
        if (e < end) { s = csr_src[e]; w = csr_w[e]; }
        const float4 xv = *(const float4*)(x + (long long)s * F + fi * 4);
        ax += w * xv.x; ay += w * xv.y; az += w * xv.z; aw += w * xv.w;
    }
#pragma unroll
    for (int m = 16; m < 64; m <<= 1) {
        ax += __shfl_xor(ax, m, 64);
        ay += __shfl_xor(ay, m, 64);
        az += __shfl_xor(az, m, 64);
        aw += __shfl_xor(aw, m, 64);
    }
    if (lane < 16) {
        float4 r = {ax, ay, az, aw};
        *(float4*)(y + (long long)wid * F + fi * 4) = r;
    }
}

// ---------------- fused feature-build + GEMM + PReLU ----------------
// Block owns ONE output quarter (blockIdx.y): W-slice 320x16 = 20 KB LDS ->
// 8 blocks/CU; all lanes read the SAME W addresses per k (LDS broadcast).
// Each thread computes 2 nodes x 16 outputs (each W read feeds 32 FMAs).
// feats = [y4, |y1-y2|, |y2-y4|, |y1-y2|(dup->merged), |y3-y2|, |y4-y3|].

__global__ __launch_bounds__(256) void fused_feat_gemm3(
    const float* __restrict__ y1, const float* __restrict__ y2,
    const float* __restrict__ y3, const float* __restrict__ y4,
    const float* __restrict__ fcw, const float* __restrict__ bias,
    const float* __restrict__ pa, float* __restrict__ out, int n)
{
    __shared__ float Wt[KEFF][16];   // [k'][oo], 20 KB
    const int q = blockIdx.y;        // output quarter 0..3
    for (int i = threadIdx.x; i < KEFF * 16; i += 256) {
        int k = i >> 4, oo = i & 15;
        int o = q * 16 + oo;
        int j = k & 63;
        float v;
        if (k < 64)       v = fcw[o * TOT + j];                                 // y4
        else if (k < 128) v = fcw[o * TOT + 64 + j] + fcw[o * TOT + 192 + j];   // |y1-y2| merged
        else if (k < 192) v = fcw[o * TOT + 128 + j];                           // |y2-y4|
        else if (k < 256) v = fcw[o * TOT + 256 + j];                           // |y3-y2|
        else              v = fcw[o * TOT + 320 + j];                           // |y4-y3|
        Wt[k][oo] = v;
    }
    __syncthreads();

    int nodeA = blockIdx.x * 512 + threadIdx.x;
    int nodeB = nodeA + 256;
    if (nodeA >= n) return;                       // after the barrier: safe
    bool hasB = nodeB < n;
    long long offB = hasB ? (long long)nodeB * F : (long long)nodeA * F;

    float accA[16], accB[16];
#pragma unroll
    for (int o = 0; o < 16; ++o) {
        float b = bias[q * 16 + o];
        accA[o] = b; accB[o] = b;
    }

    const float4* pA1 = (const float4*)(y1 + (long long)nodeA * F);
    const float4* pA2 = (const float4*)(y2 + (long long)nodeA * F);
    const float4* pA3 = (const float4*)(y3 + (long long)nodeA * F);
    const float4* pA4 = (const float4*)(y4 + (long long)nodeA * F);
    const float4* pB1 = (const float4*)(y1 + offB);
    const float4* pB2 = (const float4*)(y2 + offB);
    const float4* pB3 = (const float4*)(y3 + offB);
    const float4* pB4 = (const float4*)(y4 + offB);

    for (int t = 0; t < 16; ++t) {
        float4 a1 = pA1[t], a2 = pA2[t], a3 = pA3[t], a4 = pA4[t];
        float4 b1 = pB1[t], b2 = pB2[t], b3 = pB3[t], b4 = pB4[t];
        float cA0[4] = {a4.x, a4.y, a4.z, a4.w};
        float cA1[4] = {fabsf(a1.x - a2.x), fabsf(a1.y - a2.y),
                        fabsf(a1.z - a2.z), fabsf(a1.w - a2.w)};
        float cA2[4] = {fabsf(a2.x - a4.x), fabsf(a2.y - a4.y),
                        fabsf(a2.z - a4.z), fabsf(a2.w - a4.w)};
        float cA3[4] = {fabsf(a3.x - a2.x), fabsf(a3.y - a2.y),
                        fabsf(a3.z - a2.z), fabsf(a3.w - a2.w)};
        float cA4[4] = {fabsf(a4.x - a3.x), fabsf(a4.y - a3.y),
                        fabsf(a4.z - a3.z), fabsf(a4.w - a3.w)};
        float cB0[4] = {b4.x, b4.y, b4.z, b4.w};
        float cB1[4] = {fabsf(b1.x - b2.x), fabsf(b1.y - b2.y),
                        fabsf(b1.z - b2.z), fabsf(b1.w - b2.w)};
        float cB2[4] = {fabsf(b2.x - b4.x), fabsf(b2.y - b4.y),
                        fabsf(b2.z - b4.z), fabsf(b2.w - b4.w)};
        float cB3[4] = {fabsf(b3.x - b2.x), fabsf(b3.y - b2.y),
                        fabsf(b3.z - b2.z), fabsf(b3.w - b2.w)};
        float cB4[4] = {fabsf(b4.x - b3.x), fabsf(b4.y - b3.y),
                        fabsf(b4.z - b3.z), fabsf(b4.w - b3.w)};
#pragma unroll
        for (int j = 0; j < 4; ++j) {
            int kb = t * 4 + j;
            const float4* r0 = (const float4*)&Wt[kb][0];
            const float4* r1 = (const float4*)&Wt[64 + kb][0];
            const float4* r2 = (const float4*)&Wt[128 + kb][0];
            const float4* r3 = (const float4*)&Wt[192 + kb][0];
            const float4* r4 = (const float4*)&Wt[256 + kb][0];
#pragma unroll
            for (int u = 0; u < 4; ++u) {
                float4 w0 = r0[u], w1 = r1[u], w2 = r2[u], w3 = r3[u], w4 = r4[u];
                float sA0 = cA0[j], sA1 = cA1[j], sA2 = cA2[j], sA3 = cA3[j], sA4 = cA4[j];
                float sB0 = cB0[j], sB1 = cB1[j], sB2 = cB2[j], sB3 = cB3[j], sB4 = cB4[j];
                accA[u * 4 + 0] += sA0 * w0.x + sA1 * w1.x + sA2 * w2.x + sA3 * w3.x + sA4 * w4.x;
                accA[u * 4 + 1] += sA0 * w0.y + sA1 * w1.y + sA2 * w2.y + sA3 * w3.y + sA4 * w4.y;
                accA[u * 4 + 2] += sA0 * w0.z + sA1 * w1.z + sA2 * w2.z + sA3 * w3.z + sA4 * w4.z;
                accA[u * 4 + 3] += sA0 * w0.w + sA1 * w1.w + sA2 * w2.w + sA3 * w3.w + sA4 * w4.w;
                accB[u * 4 + 0] += sB0 * w0.x + sB1 * w1.x + sB2 * w2.x + sB3 * w3.x + sB4 * w4.x;
                accB[u * 4 + 1] += sB0 * w0.y + sB1 * w1.y + sB2 * w2.y + sB3 * w3.y + sB4 * w4.y;
                accB[u * 4 + 2] += sB0 * w0.z + sB1 * w1.z + sB2 * w2.z + sB3 * w3.z + sB4 * w4.z;
                accB[u * 4 + 3] += sB0 * w0.w + sB1 * w1.w + sB2 * w2.w + sB3 * w3.w + sB4 * w4.w;
            }
        }
    }

    float a = pa[0];
    float4* poA = (float4*)(out + (long long)nodeA * F + q * 16);
#pragma unroll
    for (int u = 0; u < 4; ++u) {
        float t0 = accA[u * 4 + 0], t1 = accA[u * 4 + 1];
        float t2 = accA[u * 4 + 2], t3 = accA[u * 4 + 3];
        float4 r;
        r.x = t0 > 0.0f ? t0 : a * t0;
        r.y = t1 > 0.0f ? t1 : a * t1;
        r.z = t2 > 0.0f ? t2 : a * t2;
        r.w = t3 > 0.0f ? t3 : a * t3;
        poA[u] = r;
    }
    if (hasB) {
        float4* poB = (float4*)(out + (long long)nodeB * F + q * 16);
#pragma unroll
        for (int u = 0; u < 4; ++u) {
            float t0 = accB[u * 4 + 0], t1 = accB[u * 4 + 1];
            float t2 = accB[u * 4 + 2], t3 = accB[u * 4 + 3];
            float4 r;
            r.x = t0 > 0.0f ? t0 : a * t0;
            r.y = t1 > 0.0f ? t1 : a * t1;
            r.z = t2 > 0.0f ? t2 : a * t2;
            r.w = t3 > 0.0f ? t3 : a * t3;
            poB[u] = r;
        }
    }
}

extern "C" void kernel_launch(void* const* d_in, const int* in_sizes, int n_in,
                              void* d_out, int out_size, void* d_ws, size_t ws_size,
                              hipStream_t stream)
{
    const float* seq  = (const float*)d_in[0];
    const int*   eidx = (const int*)d_in[1];
    const float* ew   = (const float*)d_in[2];
    const float* fcw  = (const float*)d_in[3];
    const float* bias = (const float*)d_in[4];
    const float* pa   = (const float*)d_in[5];
    float* out = (float*)d_out;

    int n  = in_sizes[0] / F;     // 50000
    int ne = in_sizes[2];         // 800000
    const int* src = eidx;        // edge_index[0]
    const int* dst = eidx + ne;   // edge_index[1]

    // workspace layout (all 4-byte elems): ~58.2 MB
    float* y1      = (float*)d_ws;
    float* y2      = y1 + (long long)n * F;
    float* y3      = y2 + (long long)n * F;
    float* y4      = y3 + (long long)n * F;
    float* csr_w   = y4 + (long long)n * F;
    int*   csr_src = (int*)(csr_w + ne);
    int*   rowptr  = csr_src + ne;
    int*   cursor  = rowptr + (n + 1);
    int*   deg     = cursor + n;

    hipMemsetAsync(deg, 0, (size_t)n * sizeof(int), stream);

    int eb = (ne + 255) / 256;
    hist_kernel<<<eb, 256, 0, stream>>>(dst, deg, ne);
    scan_kernel<<<1, 1024, 0, stream>>>(deg, rowptr, cursor, n);
    scatter_kernel<<<eb, 256, 0, stream>>>(src, dst, ew, cursor, csr_src, csr_w, ne);

    int sb = (int)(((long long)n * 64 + 255) / 256);
    spmm_pull4<<<sb, 256, 0, stream>>>(seq, y1, rowptr, csr_src, csr_w, n);
    spmm_pull4<<<sb, 256, 0, stream>>>(y1,  y2, rowptr, csr_src, csr_w, n);
    spmm_pull4<<<sb, 256, 0, stream>>>(y2,  y3, rowptr, csr_src, csr_w, n);
    spmm_pull4<<<sb, 256, 0, stream>>>(y3,  y4, rowptr, csr_src, csr_w, n);

    dim3 gb((n + 511) / 512, 4);
    fused_feat_gemm3<<<gb, 256, 0, stream>>>(y1, y2, y3, y4, fcw, bias, pa, out, n);
}